// Round 12
// baseline (435.429 us; speedup 1.0000x reference)
//
#include <hip/hip_runtime.h>
#include <hip/hip_bf16.h>
#include <cstdint>
#include <cstddef>

namespace {

constexpr int S_LEN = 2048;
constexpr int DM    = 4096;
constexpr int NH    = 32;
constexpr int NKV   = 8;
constexpr int DH    = 128;
constexpr int LTAB  = 20;
constexpr int RBKT  = 128;
constexpr int NQKV  = NH * DH + 2 * NKV * DH;  // 6144 packed Q|K|V cols
constexpr int KOFF  = NH * DH;                 // 4096
constexpr int VOFF  = NH * DH + NKV * DH;      // 5120

typedef short s16x8 __attribute__((ext_vector_type(8)));
typedef float f32x4 __attribute__((ext_vector_type(4)));
typedef unsigned long long u64;
struct u64x2 { u64 x, y; };

__device__ inline short bf16s(float f) {
  __hip_bfloat16 b = __float2bfloat16(f);
  return (short)*reinterpret_cast<unsigned short*>(&b);
}
__device__ inline float s2f(short s) {
  unsigned short u = (unsigned short)s;
  return __bfloat162float(*reinterpret_cast<__hip_bfloat16*>(&u));
}

// 64x64 f32->bf16 transpose tile body (Wt leading dim always DM)
__device__ inline void transpose64_body(const float* __restrict__ W,
                                        __hip_bfloat16* __restrict__ Wt, int N, int bx,
                                        int by, int tid, float (*tile)[65]) {
  const int kb = by * 64, nb = bx * 64;
  const int r0 = tid >> 4, c4 = (tid & 15) * 4;
#pragma unroll
  for (int it = 0; it < 4; ++it) {
    const int r = r0 + it * 16;
    float4 v = *reinterpret_cast<const float4*>(&W[(size_t)(kb + r) * N + nb + c4]);
    tile[r][c4] = v.x;
    tile[r][c4 + 1] = v.y;
    tile[r][c4 + 2] = v.z;
    tile[r][c4 + 3] = v.w;
  }
  __syncthreads();
  const int n0 = tid >> 4, k4 = (tid & 15) * 4;
#pragma unroll
  for (int it = 0; it < 4; ++it) {
    const int n = n0 + it * 16;
    ushort4 o;
    o.x = (unsigned short)bf16s(tile[k4][n]);
    o.y = (unsigned short)bf16s(tile[k4 + 1][n]);
    o.z = (unsigned short)bf16s(tile[k4 + 2][n]);
    o.w = (unsigned short)bf16s(tile[k4 + 3][n]);
    *reinterpret_cast<ushort4*>(&Wt[(size_t)(nb + n) * DM + kb + k4]) = o;
  }
}

// ------- streaming prep: cvt(2048) + Wq(4096) + Wk(1024) + Wv(1024) + Wo(4096) -------
__global__ __launch_bounds__(256) void prep_kernel(
    const float* __restrict__ hidden, const float* __restrict__ Wq,
    const float* __restrict__ Wk, const float* __restrict__ Wv,
    const float* __restrict__ Wo, __hip_bfloat16* __restrict__ hbf,
    __hip_bfloat16* __restrict__ WqkvT, __hip_bfloat16* __restrict__ WoT) {
  __shared__ float tile[64][65];
  const int b = blockIdx.x, tid = threadIdx.x;
  if (b < 2048) {  // ---- cvt: 1024 float4 per block ----
    const size_t base = (size_t)b * 1024;
#pragma unroll
    for (int it = 0; it < 4; ++it) {
      const size_t i = base + it * 256 + tid;
      float4 v = reinterpret_cast<const float4*>(hidden)[i];
      ushort4 o;
      o.x = (unsigned short)bf16s(v.x);
      o.y = (unsigned short)bf16s(v.y);
      o.z = (unsigned short)bf16s(v.z);
      o.w = (unsigned short)bf16s(v.w);
      reinterpret_cast<ushort4*>(hbf)[i] = o;
    }
    return;
  }
  const float* W;
  __hip_bfloat16* Wt;
  int N, bx, by;
  int t = b - 2048;
  if (t < 4096) {
    W = Wq; Wt = WqkvT; N = DM; bx = t & 63; by = t >> 6;
  } else if (t < 5120) {
    t -= 4096; W = Wk; Wt = WqkvT + (size_t)KOFF * DM; N = NKV * DH; bx = t & 15; by = t >> 4;
  } else if (t < 6144) {
    t -= 5120; W = Wv; Wt = WqkvT + (size_t)VOFF * DM; N = NKV * DH; bx = t & 15; by = t >> 4;
  } else {
    t -= 6144; W = Wo; Wt = WoT; N = DM; bx = t & 63; by = t >> 6;
  }
  transpose64_body(W, Wt, N, bx, by, tid, tile);
}

// ---------------- exact top-M key selection (R7-proven: 1024 thr x 2 cand) -------
__global__ __launch_bounds__(1024) void select_kernel(const float* __restrict__ q_probs,
                                                      const float* __restrict__ v_norm,
                                                      const int* __restrict__ allowed,
                                                      const int* __restrict__ k_hard,
                                                      const int* __restrict__ sinkp,
                                                      const int* __restrict__ winp,
                                                      const int* __restrict__ Mp,
                                                      int* __restrict__ sel_idx,
                                                      int* __restrict__ sel_cnt) {
  const int h = blockIdx.x;
  const int tid = threadIdx.x;
  const int lane = tid & 63;
  const int wid = tid >> 6;
  __shared__ u64 keys[S_LEN];
  __shared__ int waveTot[16];
  const int t0 = tid * 2;
  float c0 = 0.f, c1 = 0.f;
#pragma unroll
  for (int l = 0; l < LTAB; ++l) {
    const int2 kh = *reinterpret_cast<const int2*>(&k_hard[(size_t)(h * LTAB + l) * S_LEN + t0]);
    c0 += q_probs[(h * LTAB + l) * RBKT + kh.x];
    c1 += q_probs[(h * LTAB + l) * RBKT + kh.y];
  }
  const int2 al = *reinterpret_cast<const int2*>(&allowed[h * S_LEN + t0]);
  const float2 vn = *reinterpret_cast<const float2*>(&v_norm[h * S_LEN + t0]);
  const float s0 = al.x ? c0 * vn.x : -INFINITY;
  const float s1 = al.y ? c1 * vn.y : -INFINITY;
  auto mkkey = [](float s, int t) -> u64 {
    unsigned m = __float_as_uint(s);
    m = (m & 0x80000000u) ? ~m : (m | 0x80000000u);
    return ((u64)m << 11) | (u64)(S_LEN - 1 - t);
  };
  const u64 k0 = mkkey(s0, t0);
  const u64 k1 = mkkey(s1, t0 + 1);
  keys[t0] = k0;
  keys[t0 + 1] = k1;
  __syncthreads();
  int r0 = 0, r1 = 0;
#pragma unroll 8
  for (int u = 0; u < S_LEN; u += 2) {
    const u64x2 kv = *reinterpret_cast<const u64x2*>(&keys[u]);
    r0 += (kv.x > k0) + (kv.y > k0);
    r1 += (kv.x > k1) + (kv.y > k1);
  }
  const int Mv = min(Mp[0], S_LEN);
  int sv = sinkp[0];
  sv = sv < 0 ? 0 : (sv > S_LEN ? S_LEN : sv);
  int wv = winp[0];
  wv = wv < 0 ? 0 : (wv > S_LEN ? S_LEN : wv);
  int wstart = S_LEN - wv;
  if (wstart < sv) wstart = sv;
  bool sel0 = r0 < Mv, sel1 = r1 < Mv;
  if (t0 < sv) sel0 = true;
  if (t0 + 1 < sv) sel1 = true;
  if (wv > 0) {
    if (t0 >= wstart) sel0 = true;
    if (t0 + 1 >= wstart) sel1 = true;
  }
  if (sv == 0 && wv == 0) {
    if (t0 == S_LEN - 1) sel0 = true;
    if (t0 + 1 == S_LEN - 1) sel1 = true;
  }
  sel0 = sel0 && (al.x != 0);
  sel1 = sel1 && (al.y != 0);
  const int cnt = (sel0 ? 1 : 0) + (sel1 ? 1 : 0);
  int inc = cnt;
#pragma unroll
  for (int off = 1; off < 64; off <<= 1) {
    int n = __shfl_up(inc, off);
    if (lane >= off) inc += n;
  }
  if (lane == 63) waveTot[wid] = inc;
  __syncthreads();
  int wbase = 0;
  for (int w = 0; w < wid; ++w) wbase += waveTot[w];
  int pos = wbase + inc - cnt;
  if (tid == 0) {
    int tot = 0;
#pragma unroll
    for (int w = 0; w < 16; ++w) tot += waveTot[w];
    sel_cnt[h] = tot;
  }
  if (sel0) sel_idx[h * S_LEN + pos++] = t0;
  if (sel1) sel_idx[h * S_LEN + pos] = t0 + 1;
}

// ---- QKV GEMM with fused RoPE epilogue: C[2048][6144] = hbf * WqkvT^T, Q/K roped ----
// K-loop identical to the proven m97-structure gemm_bt; epilogue stages the 128x128
// output tile in LDS (padded [128][136] bf16) and applies RoPE in-tile (head = tile).
__global__ __launch_bounds__(256) void gemm_qkv_rope(const __hip_bfloat16* __restrict__ A,
                                                     const __hip_bfloat16* __restrict__ Bt,
                                                     __hip_bfloat16* __restrict__ Cout,
                                                     const float* __restrict__ cosb,
                                                     const float* __restrict__ sinb) {
  __shared__ __hip_bfloat16 smbuf[128 * 136];  // 34.8 KB: staging (32KB) U rope tile
  __hip_bfloat16* As = smbuf;
  __hip_bfloat16* Bs = smbuf + 128 * 64;
  constexpr int N = NQKV, K = DM;
  const int tid = threadIdx.x;
  const int wid = tid >> 6;
  const int lane = tid & 63;
  const int bm = blockIdx.y, bn = blockIdx.x;
  const int wr = wid >> 1, wc = wid & 1;
  f32x4 acc[4][4] = {};
  const __hip_bfloat16* Abase = A + (size_t)bm * 128 * K;
  const __hip_bfloat16* Bbase = Bt + (size_t)bn * 128 * K;
  for (int kt = 0; kt < K; kt += 64) {
    __syncthreads();
#pragma unroll
    for (int j = 0; j < 4; ++j) {
      const int pb = j * 4096 + wid * 1024;
      const int p = pb + lane * 16;
      const int row = p >> 7;
      const int slot = ((p >> 4) & 7) ^ (row & 7);
      const int goff = row * K + kt + slot * 8;
      __builtin_amdgcn_global_load_lds(
          (const __attribute__((address_space(1))) void*)(Abase + goff),
          (__attribute__((address_space(3))) void*)(As + (pb >> 1)), 16, 0, 0);
      __builtin_amdgcn_global_load_lds(
          (const __attribute__((address_space(1))) void*)(Bbase + goff),
          (__attribute__((address_space(3))) void*)(Bs + (pb >> 1)), 16, 0, 0);
    }
    __syncthreads();
#pragma unroll
    for (int kk = 0; kk < 2; ++kk) {
      s16x8 af[4], bf[4];
#pragma unroll
      for (int i = 0; i < 4; ++i) {
        const int ra = wr * 64 + i * 16 + (lane & 15);
        const int sa = (kk * 4 + (lane >> 4)) ^ (ra & 7);
        af[i] = *reinterpret_cast<const s16x8*>(As + ra * 64 + sa * 8);
        const int rb = wc * 64 + i * 16 + (lane & 15);
        const int sb = (kk * 4 + (lane >> 4)) ^ (rb & 7);
        bf[i] = *reinterpret_cast<const s16x8*>(Bs + rb * 64 + sb * 8);
      }
#pragma unroll
      for (int i = 0; i < 4; ++i)
#pragma unroll
        for (int jn = 0; jn < 4; ++jn)
          acc[i][jn] = __builtin_amdgcn_mfma_f32_16x16x32_bf16(af[i], bf[jn], acc[i][jn], 0, 0, 0);
    }
  }
  // ---- epilogue: stage tile in LDS, RoPE for Q/K blocks, plain copy for V ----
  __syncthreads();  // all waves done reading As/Bs
  const int rg = (lane >> 4) * 4;
  const int cg = lane & 15;
#pragma unroll
  for (int i = 0; i < 4; ++i)
#pragma unroll
    for (int jn = 0; jn < 4; ++jn)
#pragma unroll
      for (int r = 0; r < 4; ++r)
        smbuf[(wr * 64 + i * 16 + rg + r) * 136 + wc * 64 + jn * 16 + cg] =
            __float2bfloat16(acc[i][jn][r]);
  __syncthreads();
  const bool isV = (bn * 128) >= VOFF;
  const int srow = tid >> 1;
  const int col0 = (tid & 1) * 64;
  const int sg = bm * 128 + srow;
#pragma unroll
  for (int c = 0; c < 8; ++c) {
    const int d0 = col0 + ((c + srow) & 7) * 8;  // rotated for bank spread
    s16x8 x = *reinterpret_cast<const s16x8*>(&smbuf[srow * 136 + d0]);
    s16x8 outv;
    if (isV) {
      outv = x;
    } else {
      const s16x8 xp = *reinterpret_cast<const s16x8*>(&smbuf[srow * 136 + (d0 ^ 64)]);
      const float sgn = (d0 < 64) ? -1.f : 1.f;
      const float* cs = cosb + (size_t)sg * DH + d0;
      const float* sn = sinb + (size_t)sg * DH + d0;
#pragma unroll
      for (int j = 0; j < 8; ++j)
        outv[j] = bf16s(s2f(x[j]) * cs[j] + sgn * s2f(xp[j]) * sn[j]);
    }
    *reinterpret_cast<s16x8*>(&Cout[(size_t)sg * N + bn * 128 + d0]) = outv;
  }
}

// ---- split-K Wo GEMM: z-th K-half into P + z*M*N (f32). 1024 blocks -> 4/CU ----
__global__ __launch_bounds__(256) void gemm_bt_splitk(const __hip_bfloat16* __restrict__ A,
                                                      const __hip_bfloat16* __restrict__ Bt,
                                                      float* __restrict__ P,
                                                      int N, int Kfull, int KH) {
  __shared__ __hip_bfloat16 As[128 * 64];
  __shared__ __hip_bfloat16 Bs[128 * 64];
  const int tid = threadIdx.x;
  const int wid = tid >> 6;
  const int lane = tid & 63;
  const int bm = blockIdx.y, bn = blockIdx.x, kz = blockIdx.z;
  const int wr = wid >> 1, wc = wid & 1;
  f32x4 acc[4][4] = {};
  const __hip_bfloat16* Abase = A + (size_t)bm * 128 * Kfull + kz * KH;
  const __hip_bfloat16* Bbase = Bt + (size_t)bn * 128 * Kfull + kz * KH;
  for (int kt = 0; kt < KH; kt += 64) {
    __syncthreads();
#pragma unroll
    for (int j = 0; j < 4; ++j) {
      const int pb = j * 4096 + wid * 1024;
      const int p = pb + lane * 16;
      const int row = p >> 7;
      const int slot = ((p >> 4) & 7) ^ (row & 7);
      const int goff = row * Kfull + kt + slot * 8;
      __builtin_amdgcn_global_load_lds(
          (const __attribute__((address_space(1))) void*)(Abase + goff),
          (__attribute__((address_space(3))) void*)(As + (pb >> 1)), 16, 0, 0);
      __builtin_amdgcn_global_load_lds(
          (const __attribute__((address_space(1))) void*)(Bbase + goff),
          (__attribute__((address_space(3))) void*)(Bs + (pb >> 1)), 16, 0, 0);
    }
    __syncthreads();
#pragma unroll
    for (int kk = 0; kk < 2; ++kk) {
      s16x8 af[4], bf[4];
#pragma unroll
      for (int i = 0; i < 4; ++i) {
        const int ra = wr * 64 + i * 16 + (lane & 15);
        const int sa = (kk * 4 + (lane >> 4)) ^ (ra & 7);
        af[i] = *reinterpret_cast<const s16x8*>(As + ra * 64 + sa * 8);
        const int rb = wc * 64 + i * 16 + (lane & 15);
        const int sb = (kk * 4 + (lane >> 4)) ^ (rb & 7);
        bf[i] = *reinterpret_cast<const s16x8*>(Bs + rb * 64 + sb * 8);
      }
#pragma unroll
      for (int i = 0; i < 4; ++i)
#pragma unroll
        for (int jn = 0; jn < 4; ++jn)
          acc[i][jn] = __builtin_amdgcn_mfma_f32_16x16x32_bf16(af[i], bf[jn], acc[i][jn], 0, 0, 0);
    }
  }
  float* Pz = P + (size_t)kz * S_LEN * N;
  const int rg = (lane >> 4) * 4;
  const int cg = lane & 15;
#pragma unroll
  for (int i = 0; i < 4; ++i)
#pragma unroll
    for (int jn = 0; jn < 4; ++jn)
#pragma unroll
      for (int r = 0; r < 4; ++r) {
        const int rr = bm * 128 + wr * 64 + i * 16 + rg + r;
        const int cc = bn * 128 + wc * 64 + jn * 16 + cg;
        Pz[(size_t)rr * N + cc] = acc[i][jn][r];
      }
}

__global__ __launch_bounds__(256) void reduce_splitk(const float* __restrict__ P,
                                                     float* __restrict__ out, int n4) {
  const int i = blockIdx.x * 256 + threadIdx.x;
  if (i >= n4) return;
  const float4 a = reinterpret_cast<const float4*>(P)[i];
  const float4 b = reinterpret_cast<const float4*>(P + (size_t)S_LEN * DM)[i];
  float4 o;
  o.x = a.x + b.x;
  o.y = a.y + b.y;
  o.z = a.z + b.z;
  o.w = a.w + b.w;
  reinterpret_cast<float4*>(out)[i] = o;
}

// ---------------- flash attention, BKV=64, T14 async-staged K/V ----------------
__global__ __launch_bounds__(256) void attn_kernel(const __hip_bfloat16* __restrict__ Qkv,
                                                   const int* __restrict__ sel_idx,
                                                   const int* __restrict__ sel_cnt,
                                                   __hip_bfloat16* __restrict__ ctx) {
  constexpr int BKV = 64;
  const int h = blockIdx.y;
  const int q0 = blockIdx.x * 64;
  const int tid = threadIdx.x, wid = tid >> 6, lane = tid & 63;
  const int l15 = lane & 15, hi = lane >> 4;
  const int kv = h >> 2;
  __shared__ __hip_bfloat16 Ks[BKV][DH + 8];
  __shared__ __hip_bfloat16 Vt[DH][BKV + 8];
  __shared__ __hip_bfloat16 Ps[4][16][BKV + 8];
  __shared__ int tIdx[BKV];
  const int qbase = q0 + wid * 16;
  const float scaling = 0.08838834764831845f;
  s16x8 qf[4];
  {
    const __hip_bfloat16* qp =
        Qkv + (size_t)(qbase + l15) * NQKV + h * DH + hi * 8;
#pragma unroll
    for (int kt = 0; kt < 4; ++kt) {
      s16x8 q = *reinterpret_cast<const s16x8*>(qp + kt * 32);
#pragma unroll
      for (int j = 0; j < 8; ++j) q[j] = bf16s(s2f(q[j]) * scaling);
      qf[kt] = q;
    }
  }
  s16x8 ones;
#pragma unroll
  for (int j = 0; j < 8; ++j) ones[j] = (short)0x3F80;
  float mr[4], lr[4];
#pragma unroll
  for (int r = 0; r < 4; ++r) {
    mr[r] = -3.0e38f;
    lr[r] = 0.f;
  }
  f32x4 o[8] = {};
  const int cnt = sel_cnt[h];
  const int qmax = q0 + 63;

  // register staging state (tile currently pending LDS write)
  int tIdxReg = 0x7fffffff;
  s16x8 rK[4];
  s16x8 rV[4];
  const int vj = tid >> 2, vdp = (tid & 3) * 32;

  auto load_tile = [&](int j0) {
    const int nk = min(BKV, cnt - j0);
    if (tid < BKV) tIdxReg = (tid < nk) ? sel_idx[h * S_LEN + j0 + tid] : 0x7fffffff;
#pragma unroll
    for (int c = 0; c < 4; ++c) {
      const int ch = tid + c * 256;
      const int row = ch >> 4, c8 = ch & 15;
      const int t = sel_idx[h * S_LEN + j0 + min(row, nk - 1)];
      rK[c] = *reinterpret_cast<const s16x8*>(Qkv + (size_t)t * NQKV + KOFF + kv * DH + c8 * 8);
    }
    if (vj < nk) {
      const int t = sel_idx[h * S_LEN + j0 + vj];
      const __hip_bfloat16* vp = Qkv + (size_t)t * NQKV + VOFF + kv * DH + vdp;
#pragma unroll
      for (int c = 0; c < 4; ++c) rV[c] = *reinterpret_cast<const s16x8*>(vp + c * 8);
    } else {
#pragma unroll
      for (int c = 0; c < 4; ++c) rV[c] = s16x8{};
    }
  };

  if (cnt > 0 && sel_idx[h * S_LEN] <= qmax) {
    load_tile(0);
    for (int j0 = 0; j0 < cnt; j0 += BKV) {
      const int nk = min(BKV, cnt - j0);
      __syncthreads();
      if (tid < BKV) tIdx[tid] = tIdxReg;
#pragma unroll
      for (int c = 0; c < 4; ++c) {
        const int ch = tid + c * 256;
        const int row = ch >> 4, c8 = ch & 15;
        if (row < nk) *reinterpret_cast<s16x8*>(&Ks[row][c8 * 8]) = rK[c];
      }
      {
        const int ccA = vj ^ (((vdp >> 4) & 7) << 3);
        const int ccB = vj ^ ((((vdp >> 4) + 1) & 7) << 3);
#pragma unroll
        for (int i = 0; i < 8; ++i) reinterpret_cast<short&>(Vt[vdp + i][ccA]) = rV[0][i];
#pragma unroll
        for (int i = 0; i < 8; ++i) reinterpret_cast<short&>(Vt[vdp + 8 + i][ccA]) = rV[1][i];
#pragma unroll
        for (int i = 0; i < 8; ++i) reinterpret_cast<short&>(Vt[vdp + 16 + i][ccB]) = rV[2][i];
#pragma unroll
        for (int i = 0; i < 8; ++i) reinterpret_cast<short&>(Vt[vdp + 24 + i][ccB]) = rV[3][i];
      }
      // issue NEXT tile's global loads (overlap with barrier + compute below)
      const int jn0 = j0 + BKV;
      const bool more = (jn0 < cnt) && (sel_idx[h * S_LEN + jn0] <= qmax);
      if (more) load_tile(jn0);
      __syncthreads();
      // ---- compute tile j0 ----
      f32x4 sc[4];
#pragma unroll
      for (int kc = 0; kc < 4; ++kc) sc[kc] = f32x4{0.f, 0.f, 0.f, 0.f};
#pragma unroll
      for (int kt = 0; kt < 4; ++kt) {
#pragma unroll
        for (int kc = 0; kc < 4; ++kc) {
          const s16x8 kf =
              *reinterpret_cast<const s16x8*>(&Ks[kc * 16 + l15][kt * 32 + hi * 8]);
          sc[kc] = __builtin_amdgcn_mfma_f32_16x16x32_bf16(qf[kt], kf, sc[kc], 0, 0, 0);
        }
      }
      int tt[4];
#pragma unroll
      for (int kc = 0; kc < 4; ++kc) tt[kc] = tIdx[kc * 16 + l15];
      float vv[4][4];
      bool need = false;
#pragma unroll
      for (int r = 0; r < 4; ++r) {
        const int qs = qbase + (hi << 2) + r;
        float mx = -3.0e38f;
#pragma unroll
        for (int kc = 0; kc < 4; ++kc) {
          vv[kc][r] = (tt[kc] <= qs) ? sc[kc][r] : -1.0e9f;
          mx = fmaxf(mx, vv[kc][r]);
        }
        need = need || (mx > mr[r] + 8.f);
      }
      if (__any(need)) {
#pragma unroll
        for (int r = 0; r < 4; ++r) {
          float m = fmaxf(fmaxf(vv[0][r], vv[1][r]), fmaxf(vv[2][r], vv[3][r]));
#pragma unroll
          for (int off = 1; off < 16; off <<= 1) m = fmaxf(m, __shfl_xor(m, off));
          const float mn = fmaxf(mr[r], m);
          const float scl = __expf(mr[r] - mn);
          lr[r] *= scl;
#pragma unroll
          for (int nt = 0; nt < 8; ++nt) o[nt][r] *= scl;
          mr[r] = mn;
        }
      }
#pragma unroll
      for (int r = 0; r < 4; ++r) {
#pragma unroll
        for (int kc = 0; kc < 4; ++kc) {
          Ps[wid][(hi << 2) + r][kc * 16 + l15] = __float2bfloat16(__expf(vv[kc][r] - mr[r]));
        }
      }
      const s16x8 pf0 = *reinterpret_cast<const s16x8*>(&Ps[wid][l15][hi * 8]);
      const s16x8 pf1 = *reinterpret_cast<const s16x8*>(&Ps[wid][l15][32 + hi * 8]);
      {
        f32x4 zero = {0.f, 0.f, 0.f, 0.f};
        f32x4 ps = __builtin_amdgcn_mfma_f32_16x16x32_bf16(pf0, ones, zero, 0, 0, 0);
        ps = __builtin_amdgcn_mfma_f32_16x16x32_bf16(pf1, ones, ps, 0, 0, 0);
#pragma unroll
        for (int r = 0; r < 4; ++r) lr[r] += ps[r];
      }
#pragma unroll
      for (int nt = 0; nt < 8; ++nt) {
        const s16x8 vfa =
            *reinterpret_cast<const s16x8*>(&Vt[nt * 16 + l15][(hi * 8) ^ (nt * 8)]);
        const s16x8 vfb =
            *reinterpret_cast<const s16x8*>(&Vt[nt * 16 + l15][(32 + hi * 8) ^ (nt * 8)]);
        o[nt] = __builtin_amdgcn_mfma_f32_16x16x32_bf16(pf0, vfa, o[nt], 0, 0, 0);
        o[nt] = __builtin_amdgcn_mfma_f32_16x16x32_bf16(pf1, vfb, o[nt], 0, 0, 0);
      }
      if (!more) break;
    }
  }
#pragma unroll
  for (int nt = 0; nt < 8; ++nt)
#pragma unroll
    for (int r = 0; r < 4; ++r) {
      const int qs = qbase + (hi << 2) + r;
      const int d = nt * 16 + l15;
      ctx[(size_t)qs * (NH * DH) + h * DH + d] = __float2bfloat16(o[nt][r] / lr[r]);
    }
}

}  // namespace

extern "C" void kernel_launch(void* const* d_in, const int* in_sizes, int n_in,
                              void* d_out, int out_size, void* d_ws, size_t ws_size,
                              hipStream_t stream) {
  const float* hidden = (const float*)d_in[0];
  const float* cosb = (const float*)d_in[1];
  const float* sinb = (const float*)d_in[2];
  const float* q_probs = (const float*)d_in[3];
  const float* v_norm = (const float*)d_in[4];
  const int* allowed = (const int*)d_in[5];
  const int* k_hard = (const int*)d_in[6];
  const float* Wq = (const float*)d_in[7];
  const float* Wk = (const float*)d_in[8];
  const float* Wv = (const float*)d_in[9];
  const float* Wo = (const float*)d_in[10];
  const int* sinkp = (const int*)d_in[11];
  const int* winp = (const int*)d_in[12];
  const int* Mp = (const int*)d_in[13];

  char* ws = (char*)d_ws;
  size_t off = 0;
  auto alloc = [&](size_t bytes) -> char* {
    char* p = ws + off;
    off += (bytes + 255) & ~(size_t)255;
    return p;
  };
  __hip_bfloat16* hbf = (__hip_bfloat16*)alloc((size_t)S_LEN * DM * 2);
  __hip_bfloat16* WqkvT = (__hip_bfloat16*)alloc((size_t)NQKV * DM * 2);  // packed [6144][4096]
  __hip_bfloat16* WoT = (__hip_bfloat16*)alloc((size_t)DM * DM * 2);
  __hip_bfloat16* QKV = (__hip_bfloat16*)alloc((size_t)S_LEN * NQKV * 2);  // roped in-place
  __hip_bfloat16* ctx = (__hip_bfloat16*)alloc((size_t)S_LEN * NH * DH * 2);
  int* sel_idx = (int*)alloc((size_t)NH * S_LEN * 4);
  int* sel_cnt = (int*)alloc((size_t)NH * 4);
  if (off > ws_size) return;
  // split-K partials (2 x 33.5 MB f32) overlay hbf+WqkvT, dead after QKV GEMM.
  float* Psplit = (float*)hbf;

  prep_kernel<<<12288, 256, 0, stream>>>(hidden, Wq, Wk, Wv, Wo, hbf, WqkvT, WoT);

  select_kernel<<<NH, 1024, 0, stream>>>(q_probs, v_norm, allowed, k_hard, sinkp, winp, Mp,
                                         sel_idx, sel_cnt);

  gemm_qkv_rope<<<dim3(NQKV / 128, S_LEN / 128), 256, 0, stream>>>(hbf, WqkvT, QKV, cosb,
                                                                   sinb);

  attn_kernel<<<dim3(S_LEN / 64, NH), 256, 0, stream>>>(QKV, sel_idx, sel_cnt, ctx);

  gemm_bt_splitk<<<dim3(DM / 128, S_LEN / 128, 2), 256, 0, stream>>>(ctx, WoT, Psplit, DM,
                                                                     DM, DM / 2);
  reduce_splitk<<<(S_LEN * DM / 4 + 255) / 256, 256, 0, stream>>>((const float*)Psplit,
                                                                  (float*)d_out,
                                                                  S_LEN * DM / 4);
}

// Round 13
// 395.331 us; speedup vs baseline: 1.1014x; 1.1014x over previous
//
#include <hip/hip_runtime.h>
#include <hip/hip_bf16.h>
#include <cstdint>
#include <cstddef>

namespace {

constexpr int S_LEN = 2048;
constexpr int DM    = 4096;
constexpr int NH    = 32;
constexpr int NKV   = 8;
constexpr int DH    = 128;
constexpr int LTAB  = 20;
constexpr int RBKT  = 128;
constexpr int NQKV  = NH * DH + 2 * NKV * DH;  // 6144 packed Q|K|V cols
constexpr int KOFF  = NH * DH;                 // 4096
constexpr int VOFF  = NH * DH + NKV * DH;      // 5120

typedef short s16x8 __attribute__((ext_vector_type(8)));
typedef float f32x4 __attribute__((ext_vector_type(4)));
typedef unsigned long long u64;
struct u64x2 { u64 x, y; };

__device__ inline short bf16s(float f) {
  __hip_bfloat16 b = __float2bfloat16(f);
  return (short)*reinterpret_cast<unsigned short*>(&b);
}
__device__ inline float s2f(short s) {
  unsigned short u = (unsigned short)s;
  return __bfloat162float(*reinterpret_cast<__hip_bfloat16*>(&u));
}

// 64x64 f32->bf16 transpose tile body (Wt leading dim always DM)
__device__ inline void transpose64_body(const float* __restrict__ W,
                                        __hip_bfloat16* __restrict__ Wt, int N, int bx,
                                        int by, int tid, float (*tile)[65]) {
  const int kb = by * 64, nb = bx * 64;
  const int r0 = tid >> 4, c4 = (tid & 15) * 4;
#pragma unroll
  for (int it = 0; it < 4; ++it) {
    const int r = r0 + it * 16;
    float4 v = *reinterpret_cast<const float4*>(&W[(size_t)(kb + r) * N + nb + c4]);
    tile[r][c4] = v.x;
    tile[r][c4 + 1] = v.y;
    tile[r][c4 + 2] = v.z;
    tile[r][c4 + 3] = v.w;
  }
  __syncthreads();
  const int n0 = tid >> 4, k4 = (tid & 15) * 4;
#pragma unroll
  for (int it = 0; it < 4; ++it) {
    const int n = n0 + it * 16;
    ushort4 o;
    o.x = (unsigned short)bf16s(tile[k4][n]);
    o.y = (unsigned short)bf16s(tile[k4 + 1][n]);
    o.z = (unsigned short)bf16s(tile[k4 + 2][n]);
    o.w = (unsigned short)bf16s(tile[k4 + 3][n]);
    *reinterpret_cast<ushort4*>(&Wt[(size_t)(nb + n) * DM + kb + k4]) = o;
  }
}

// ------- streaming prep: cvt(2048) + Wq(4096) + Wk(1024) + Wv(1024) + Wo(4096) -------
__global__ __launch_bounds__(256) void prep_kernel(
    const float* __restrict__ hidden, const float* __restrict__ Wq,
    const float* __restrict__ Wk, const float* __restrict__ Wv,
    const float* __restrict__ Wo, __hip_bfloat16* __restrict__ hbf,
    __hip_bfloat16* __restrict__ WqkvT, __hip_bfloat16* __restrict__ WoT) {
  __shared__ float tile[64][65];
  const int b = blockIdx.x, tid = threadIdx.x;
  if (b < 2048) {  // ---- cvt: 1024 float4 per block ----
    const size_t base = (size_t)b * 1024;
#pragma unroll
    for (int it = 0; it < 4; ++it) {
      const size_t i = base + it * 256 + tid;
      float4 v = reinterpret_cast<const float4*>(hidden)[i];
      ushort4 o;
      o.x = (unsigned short)bf16s(v.x);
      o.y = (unsigned short)bf16s(v.y);
      o.z = (unsigned short)bf16s(v.z);
      o.w = (unsigned short)bf16s(v.w);
      reinterpret_cast<ushort4*>(hbf)[i] = o;
    }
    return;
  }
  const float* W;
  __hip_bfloat16* Wt;
  int N, bx, by;
  int t = b - 2048;
  if (t < 4096) {
    W = Wq; Wt = WqkvT; N = DM; bx = t & 63; by = t >> 6;
  } else if (t < 5120) {
    t -= 4096; W = Wk; Wt = WqkvT + (size_t)KOFF * DM; N = NKV * DH; bx = t & 15; by = t >> 4;
  } else if (t < 6144) {
    t -= 5120; W = Wv; Wt = WqkvT + (size_t)VOFF * DM; N = NKV * DH; bx = t & 15; by = t >> 4;
  } else {
    t -= 6144; W = Wo; Wt = WoT; N = DM; bx = t & 63; by = t >> 6;
  }
  transpose64_body(W, Wt, N, bx, by, tid, tile);
}

// ---------------- exact top-M key selection (R7-proven: 1024 thr x 2 cand) -------
__global__ __launch_bounds__(1024) void select_kernel(const float* __restrict__ q_probs,
                                                      const float* __restrict__ v_norm,
                                                      const int* __restrict__ allowed,
                                                      const int* __restrict__ k_hard,
                                                      const int* __restrict__ sinkp,
                                                      const int* __restrict__ winp,
                                                      const int* __restrict__ Mp,
                                                      int* __restrict__ sel_idx,
                                                      int* __restrict__ sel_cnt) {
  const int h = blockIdx.x;
  const int tid = threadIdx.x;
  const int lane = tid & 63;
  const int wid = tid >> 6;
  __shared__ u64 keys[S_LEN];
  __shared__ int waveTot[16];
  const int t0 = tid * 2;
  float c0 = 0.f, c1 = 0.f;
#pragma unroll
  for (int l = 0; l < LTAB; ++l) {
    const int2 kh = *reinterpret_cast<const int2*>(&k_hard[(size_t)(h * LTAB + l) * S_LEN + t0]);
    c0 += q_probs[(h * LTAB + l) * RBKT + kh.x];
    c1 += q_probs[(h * LTAB + l) * RBKT + kh.y];
  }
  const int2 al = *reinterpret_cast<const int2*>(&allowed[h * S_LEN + t0]);
  const float2 vn = *reinterpret_cast<const float2*>(&v_norm[h * S_LEN + t0]);
  const float s0 = al.x ? c0 * vn.x : -INFINITY;
  const float s1 = al.y ? c1 * vn.y : -INFINITY;
  auto mkkey = [](float s, int t) -> u64 {
    unsigned m = __float_as_uint(s);
    m = (m & 0x80000000u) ? ~m : (m | 0x80000000u);
    return ((u64)m << 11) | (u64)(S_LEN - 1 - t);
  };
  const u64 k0 = mkkey(s0, t0);
  const u64 k1 = mkkey(s1, t0 + 1);
  keys[t0] = k0;
  keys[t0 + 1] = k1;
  __syncthreads();
  int r0 = 0, r1 = 0;
#pragma unroll 8
  for (int u = 0; u < S_LEN; u += 2) {
    const u64x2 kv = *reinterpret_cast<const u64x2*>(&keys[u]);
    r0 += (kv.x > k0) + (kv.y > k0);
    r1 += (kv.x > k1) + (kv.y > k1);
  }
  const int Mv = min(Mp[0], S_LEN);
  int sv = sinkp[0];
  sv = sv < 0 ? 0 : (sv > S_LEN ? S_LEN : sv);
  int wv = winp[0];
  wv = wv < 0 ? 0 : (wv > S_LEN ? S_LEN : wv);
  int wstart = S_LEN - wv;
  if (wstart < sv) wstart = sv;
  bool sel0 = r0 < Mv, sel1 = r1 < Mv;
  if (t0 < sv) sel0 = true;
  if (t0 + 1 < sv) sel1 = true;
  if (wv > 0) {
    if (t0 >= wstart) sel0 = true;
    if (t0 + 1 >= wstart) sel1 = true;
  }
  if (sv == 0 && wv == 0) {
    if (t0 == S_LEN - 1) sel0 = true;
    if (t0 + 1 == S_LEN - 1) sel1 = true;
  }
  sel0 = sel0 && (al.x != 0);
  sel1 = sel1 && (al.y != 0);
  const int cnt = (sel0 ? 1 : 0) + (sel1 ? 1 : 0);
  int inc = cnt;
#pragma unroll
  for (int off = 1; off < 64; off <<= 1) {
    int n = __shfl_up(inc, off);
    if (lane >= off) inc += n;
  }
  if (lane == 63) waveTot[wid] = inc;
  __syncthreads();
  int wbase = 0;
  for (int w = 0; w < wid; ++w) wbase += waveTot[w];
  int pos = wbase + inc - cnt;
  if (tid == 0) {
    int tot = 0;
#pragma unroll
    for (int w = 0; w < 16; ++w) tot += waveTot[w];
    sel_cnt[h] = tot;
  }
  if (sel0) sel_idx[h * S_LEN + pos++] = t0;
  if (sel1) sel_idx[h * S_LEN + pos] = t0 + 1;
}

// ---------------- bf16 GEMM: C[M][N] = A[M][K] * Bt[N][K]^T ----------------
// 128x128 tile, BK=64, 4 waves (2x2), mfma 16x16x32, swizzled global_load_lds staging.
// NOTE: keep LDS at exactly 32 KB and VGPR<=80 — R9/R12 measured that any epilogue
// growing either collapses occupancy (5->4 blocks/CU) and costs ~70% runtime.
template <bool OUT_F32>
__global__ __launch_bounds__(256) void gemm_bt(const __hip_bfloat16* __restrict__ A,
                                               const __hip_bfloat16* __restrict__ Bt,
                                               void* __restrict__ Cout,
                                               int N, int K) {
  __shared__ __hip_bfloat16 As[128 * 64];
  __shared__ __hip_bfloat16 Bs[128 * 64];
  const int tid = threadIdx.x;
  const int wid = tid >> 6;
  const int lane = tid & 63;
  const int bm = blockIdx.y, bn = blockIdx.x;
  const int wr = wid >> 1, wc = wid & 1;
  f32x4 acc[4][4] = {};
  const __hip_bfloat16* Abase = A + (size_t)bm * 128 * K;
  const __hip_bfloat16* Bbase = Bt + (size_t)bn * 128 * K;
  for (int kt = 0; kt < K; kt += 64) {
    __syncthreads();
#pragma unroll
    for (int j = 0; j < 4; ++j) {
      const int pb = j * 4096 + wid * 1024;
      const int p = pb + lane * 16;
      const int row = p >> 7;
      const int slot = ((p >> 4) & 7) ^ (row & 7);
      const int goff = row * K + kt + slot * 8;
      __builtin_amdgcn_global_load_lds(
          (const __attribute__((address_space(1))) void*)(Abase + goff),
          (__attribute__((address_space(3))) void*)(As + (pb >> 1)), 16, 0, 0);
      __builtin_amdgcn_global_load_lds(
          (const __attribute__((address_space(1))) void*)(Bbase + goff),
          (__attribute__((address_space(3))) void*)(Bs + (pb >> 1)), 16, 0, 0);
    }
    __syncthreads();
#pragma unroll
    for (int kk = 0; kk < 2; ++kk) {
      s16x8 af[4], bf[4];
#pragma unroll
      for (int i = 0; i < 4; ++i) {
        const int ra = wr * 64 + i * 16 + (lane & 15);
        const int sa = (kk * 4 + (lane >> 4)) ^ (ra & 7);
        af[i] = *reinterpret_cast<const s16x8*>(As + ra * 64 + sa * 8);
        const int rb = wc * 64 + i * 16 + (lane & 15);
        const int sb = (kk * 4 + (lane >> 4)) ^ (rb & 7);
        bf[i] = *reinterpret_cast<const s16x8*>(Bs + rb * 64 + sb * 8);
      }
#pragma unroll
      for (int i = 0; i < 4; ++i)
#pragma unroll
        for (int jn = 0; jn < 4; ++jn)
          acc[i][jn] = __builtin_amdgcn_mfma_f32_16x16x32_bf16(af[i], bf[jn], acc[i][jn], 0, 0, 0);
    }
  }
  const int rg = (lane >> 4) * 4;
  const int cg = lane & 15;
#pragma unroll
  for (int i = 0; i < 4; ++i)
#pragma unroll
    for (int jn = 0; jn < 4; ++jn)
#pragma unroll
      for (int r = 0; r < 4; ++r) {
        const int rr = bm * 128 + wr * 64 + i * 16 + rg + r;
        const int cc = bn * 128 + wc * 64 + jn * 16 + cg;
        if (OUT_F32)
          reinterpret_cast<float*>(Cout)[(size_t)rr * N + cc] = acc[i][jn][r];
        else
          reinterpret_cast<__hip_bfloat16*>(Cout)[(size_t)rr * N + cc] =
              __float2bfloat16(acc[i][jn][r]);
      }
}

// ---- split-K Wo GEMM: z-th K-half into P + z*M*N (f32). 1024 blocks -> 4/CU ----
__global__ __launch_bounds__(256) void gemm_bt_splitk(const __hip_bfloat16* __restrict__ A,
                                                      const __hip_bfloat16* __restrict__ Bt,
                                                      float* __restrict__ P,
                                                      int N, int Kfull, int KH) {
  __shared__ __hip_bfloat16 As[128 * 64];
  __shared__ __hip_bfloat16 Bs[128 * 64];
  const int tid = threadIdx.x;
  const int wid = tid >> 6;
  const int lane = tid & 63;
  const int bm = blockIdx.y, bn = blockIdx.x, kz = blockIdx.z;
  const int wr = wid >> 1, wc = wid & 1;
  f32x4 acc[4][4] = {};
  const __hip_bfloat16* Abase = A + (size_t)bm * 128 * Kfull + kz * KH;
  const __hip_bfloat16* Bbase = Bt + (size_t)bn * 128 * Kfull + kz * KH;
  for (int kt = 0; kt < KH; kt += 64) {
    __syncthreads();
#pragma unroll
    for (int j = 0; j < 4; ++j) {
      const int pb = j * 4096 + wid * 1024;
      const int p = pb + lane * 16;
      const int row = p >> 7;
      const int slot = ((p >> 4) & 7) ^ (row & 7);
      const int goff = row * Kfull + kt + slot * 8;
      __builtin_amdgcn_global_load_lds(
          (const __attribute__((address_space(1))) void*)(Abase + goff),
          (__attribute__((address_space(3))) void*)(As + (pb >> 1)), 16, 0, 0);
      __builtin_amdgcn_global_load_lds(
          (const __attribute__((address_space(1))) void*)(Bbase + goff),
          (__attribute__((address_space(3))) void*)(Bs + (pb >> 1)), 16, 0, 0);
    }
    __syncthreads();
#pragma unroll
    for (int kk = 0; kk < 2; ++kk) {
      s16x8 af[4], bf[4];
#pragma unroll
      for (int i = 0; i < 4; ++i) {
        const int ra = wr * 64 + i * 16 + (lane & 15);
        const int sa = (kk * 4 + (lane >> 4)) ^ (ra & 7);
        af[i] = *reinterpret_cast<const s16x8*>(As + ra * 64 + sa * 8);
        const int rb = wc * 64 + i * 16 + (lane & 15);
        const int sb = (kk * 4 + (lane >> 4)) ^ (rb & 7);
        bf[i] = *reinterpret_cast<const s16x8*>(Bs + rb * 64 + sb * 8);
      }
#pragma unroll
      for (int i = 0; i < 4; ++i)
#pragma unroll
        for (int jn = 0; jn < 4; ++jn)
          acc[i][jn] = __builtin_amdgcn_mfma_f32_16x16x32_bf16(af[i], bf[jn], acc[i][jn], 0, 0, 0);
    }
  }
  float* Pz = P + (size_t)kz * S_LEN * N;
  const int rg = (lane >> 4) * 4;
  const int cg = lane & 15;
#pragma unroll
  for (int i = 0; i < 4; ++i)
#pragma unroll
    for (int jn = 0; jn < 4; ++jn)
#pragma unroll
      for (int r = 0; r < 4; ++r) {
        const int rr = bm * 128 + wr * 64 + i * 16 + rg + r;
        const int cc = bn * 128 + wc * 64 + jn * 16 + cg;
        Pz[(size_t)rr * N + cc] = acc[i][jn][r];
      }
}

__global__ __launch_bounds__(256) void reduce_splitk(const float* __restrict__ P,
                                                     float* __restrict__ out, int n4) {
  const int i = blockIdx.x * 256 + threadIdx.x;
  if (i >= n4) return;
  const float4 a = reinterpret_cast<const float4*>(P)[i];
  const float4 b = reinterpret_cast<const float4*>(P + (size_t)S_LEN * DM)[i];
  float4 o;
  o.x = a.x + b.x;
  o.y = a.y + b.y;
  o.z = a.z + b.z;
  o.w = a.w + b.w;
  reinterpret_cast<float4*>(out)[i] = o;
}

// ---------------- RoPE on packed QKV -> Qro [S][4096], Kro [S][1024] ----------------
__global__ __launch_bounds__(256) void rope_kernel(const __hip_bfloat16* __restrict__ QKV,
                                                   const float* __restrict__ cosb,
                                                   const float* __restrict__ sinb,
                                                   __hip_bfloat16* __restrict__ Qro,
                                                   __hip_bfloat16* __restrict__ Kro) {
  const int s = blockIdx.x;
  const int tid = threadIdx.x;
  const float* cs = cosb + s * DH;
  const float* sn = sinb + s * DH;
  const __hip_bfloat16* row = QKV + (size_t)s * NQKV;
  for (int ch = tid; ch < 512 + 128; ch += 256) {
    const bool isQ = ch < 512;
    const int idx8 = (isQ ? ch : ch - 512) * 8;
    const int d8 = idx8 & (DH - 1);
    const int hb = idx8 - d8;
    const __hip_bfloat16* src = isQ ? row : row + KOFF;
    s16x8 v = *reinterpret_cast<const s16x8*>(src + idx8);
    s16x8 p = *reinterpret_cast<const s16x8*>(src + hb + (d8 ^ 64));
    const float sgn = (d8 < 64) ? -1.f : 1.f;
    s16x8 outv;
#pragma unroll
    for (int j = 0; j < 8; ++j) {
      const float r = s2f(v[j]) * cs[d8 + j] + sgn * s2f(p[j]) * sn[d8 + j];
      outv[j] = bf16s(r);
    }
    if (isQ)
      *reinterpret_cast<s16x8*>(Qro + (size_t)s * (NH * DH) + idx8) = outv;
    else
      *reinterpret_cast<s16x8*>(Kro + (size_t)s * (NKV * DH) + idx8) = outv;
  }
}

// ---------------- flash attention, BKV=64, T14 async-staged K/V ----------------
__global__ __launch_bounds__(256) void attn_kernel(const __hip_bfloat16* __restrict__ Qro,
                                                   const __hip_bfloat16* __restrict__ Kro,
                                                   const __hip_bfloat16* __restrict__ Vpk,
                                                   const int* __restrict__ sel_idx,
                                                   const int* __restrict__ sel_cnt,
                                                   __hip_bfloat16* __restrict__ ctx) {
  constexpr int BKV = 64;
  const int h = blockIdx.y;
  const int q0 = blockIdx.x * 64;
  const int tid = threadIdx.x, wid = tid >> 6, lane = tid & 63;
  const int l15 = lane & 15, hi = lane >> 4;
  const int kv = h >> 2;
  __shared__ __hip_bfloat16 Ks[BKV][DH + 8];
  __shared__ __hip_bfloat16 Vt[DH][BKV + 8];
  __shared__ __hip_bfloat16 Ps[4][16][BKV + 8];
  __shared__ int tIdx[BKV];
  const int qbase = q0 + wid * 16;
  const float scaling = 0.08838834764831845f;
  s16x8 qf[4];
  {
    const __hip_bfloat16* qp =
        Qro + (size_t)(qbase + l15) * (NH * DH) + h * DH + hi * 8;
#pragma unroll
    for (int kt = 0; kt < 4; ++kt) {
      s16x8 q = *reinterpret_cast<const s16x8*>(qp + kt * 32);
#pragma unroll
      for (int j = 0; j < 8; ++j) q[j] = bf16s(s2f(q[j]) * scaling);
      qf[kt] = q;
    }
  }
  s16x8 ones;
#pragma unroll
  for (int j = 0; j < 8; ++j) ones[j] = (short)0x3F80;
  float mr[4], lr[4];
#pragma unroll
  for (int r = 0; r < 4; ++r) {
    mr[r] = -3.0e38f;
    lr[r] = 0.f;
  }
  f32x4 o[8] = {};
  const int cnt = sel_cnt[h];
  const int qmax = q0 + 63;

  // T14 register staging (next tile's K/V issued before current tile's compute)
  int tIdxReg = 0x7fffffff;
  s16x8 rK[4];
  s16x8 rV[4];
  const int vj = tid >> 2, vdp = (tid & 3) * 32;

  auto load_tile = [&](int j0) {
    const int nk = min(BKV, cnt - j0);
    if (tid < BKV) tIdxReg = (tid < nk) ? sel_idx[h * S_LEN + j0 + tid] : 0x7fffffff;
#pragma unroll
    for (int c = 0; c < 4; ++c) {
      const int ch = tid + c * 256;
      const int row = ch >> 4, c8 = ch & 15;
      const int t = sel_idx[h * S_LEN + j0 + min(row, nk - 1)];
      rK[c] = *reinterpret_cast<const s16x8*>(Kro + (size_t)t * (NKV * DH) + kv * DH + c8 * 8);
    }
    if (vj < nk) {
      const int t = sel_idx[h * S_LEN + j0 + vj];
      const __hip_bfloat16* vp = Vpk + (size_t)t * NQKV + kv * DH + vdp;
#pragma unroll
      for (int c = 0; c < 4; ++c) rV[c] = *reinterpret_cast<const s16x8*>(vp + c * 8);
    } else {
#pragma unroll
      for (int c = 0; c < 4; ++c) rV[c] = s16x8{};
    }
  };

  if (cnt > 0 && sel_idx[h * S_LEN] <= qmax) {
    load_tile(0);
    for (int j0 = 0; j0 < cnt; j0 += BKV) {
      const int nk = min(BKV, cnt - j0);
      __syncthreads();
      if (tid < BKV) tIdx[tid] = tIdxReg;
#pragma unroll
      for (int c = 0; c < 4; ++c) {
        const int ch = tid + c * 256;
        const int row = ch >> 4, c8 = ch & 15;
        if (row < nk) *reinterpret_cast<s16x8*>(&Ks[row][c8 * 8]) = rK[c];
      }
      {
        const int ccA = vj ^ (((vdp >> 4) & 7) << 3);
        const int ccB = vj ^ ((((vdp >> 4) + 1) & 7) << 3);
#pragma unroll
        for (int i = 0; i < 8; ++i) reinterpret_cast<short&>(Vt[vdp + i][ccA]) = rV[0][i];
#pragma unroll
        for (int i = 0; i < 8; ++i) reinterpret_cast<short&>(Vt[vdp + 8 + i][ccA]) = rV[1][i];
#pragma unroll
        for (int i = 0; i < 8; ++i) reinterpret_cast<short&>(Vt[vdp + 16 + i][ccB]) = rV[2][i];
#pragma unroll
        for (int i = 0; i < 8; ++i) reinterpret_cast<short&>(Vt[vdp + 24 + i][ccB]) = rV[3][i];
      }
      const int jn0 = j0 + BKV;
      const bool more = (jn0 < cnt) && (sel_idx[h * S_LEN + jn0] <= qmax);
      if (more) load_tile(jn0);
      __syncthreads();
      // ---- compute tile j0 ----
      f32x4 sc[4];
#pragma unroll
      for (int kc = 0; kc < 4; ++kc) sc[kc] = f32x4{0.f, 0.f, 0.f, 0.f};
#pragma unroll
      for (int kt = 0; kt < 4; ++kt) {
#pragma unroll
        for (int kc = 0; kc < 4; ++kc) {
          const s16x8 kf =
              *reinterpret_cast<const s16x8*>(&Ks[kc * 16 + l15][kt * 32 + hi * 8]);
          sc[kc] = __builtin_amdgcn_mfma_f32_16x16x32_bf16(qf[kt], kf, sc[kc], 0, 0, 0);
        }
      }
      int tt[4];
#pragma unroll
      for (int kc = 0; kc < 4; ++kc) tt[kc] = tIdx[kc * 16 + l15];
      float vv[4][4];
      bool need = false;
#pragma unroll
      for (int r = 0; r < 4; ++r) {
        const int qs = qbase + (hi << 2) + r;
        float mx = -3.0e38f;
#pragma unroll
        for (int kc = 0; kc < 4; ++kc) {
          vv[kc][r] = (tt[kc] <= qs) ? sc[kc][r] : -1.0e9f;
          mx = fmaxf(mx, vv[kc][r]);
        }
        need = need || (mx > mr[r] + 8.f);
      }
      if (__any(need)) {
#pragma unroll
        for (int r = 0; r < 4; ++r) {
          float m = fmaxf(fmaxf(vv[0][r], vv[1][r]), fmaxf(vv[2][r], vv[3][r]));
#pragma unroll
          for (int off = 1; off < 16; off <<= 1) m = fmaxf(m, __shfl_xor(m, off));
          const float mn = fmaxf(mr[r], m);
          const float scl = __expf(mr[r] - mn);
          lr[r] *= scl;
#pragma unroll
          for (int nt = 0; nt < 8; ++nt) o[nt][r] *= scl;
          mr[r] = mn;
        }
      }
#pragma unroll
      for (int r = 0; r < 4; ++r) {
#pragma unroll
        for (int kc = 0; kc < 4; ++kc) {
          Ps[wid][(hi << 2) + r][kc * 16 + l15] = __float2bfloat16(__expf(vv[kc][r] - mr[r]));
        }
      }
      const s16x8 pf0 = *reinterpret_cast<const s16x8*>(&Ps[wid][l15][hi * 8]);
      const s16x8 pf1 = *reinterpret_cast<const s16x8*>(&Ps[wid][l15][32 + hi * 8]);
      {
        f32x4 zero = {0.f, 0.f, 0.f, 0.f};
        f32x4 ps = __builtin_amdgcn_mfma_f32_16x16x32_bf16(pf0, ones, zero, 0, 0, 0);
        ps = __builtin_amdgcn_mfma_f32_16x16x32_bf16(pf1, ones, ps, 0, 0, 0);
#pragma unroll
        for (int r = 0; r < 4; ++r) lr[r] += ps[r];
      }
#pragma unroll
      for (int nt = 0; nt < 8; ++nt) {
        const s16x8 vfa =
            *reinterpret_cast<const s16x8*>(&Vt[nt * 16 + l15][(hi * 8) ^ (nt * 8)]);
        const s16x8 vfb =
            *reinterpret_cast<const s16x8*>(&Vt[nt * 16 + l15][(32 + hi * 8) ^ (nt * 8)]);
        o[nt] = __builtin_amdgcn_mfma_f32_16x16x32_bf16(pf0, vfa, o[nt], 0, 0, 0);
        o[nt] = __builtin_amdgcn_mfma_f32_16x16x32_bf16(pf1, vfb, o[nt], 0, 0, 0);
      }
      if (!more) break;
    }
  }
#pragma unroll
  for (int nt = 0; nt < 8; ++nt)
#pragma unroll
    for (int r = 0; r < 4; ++r) {
      const int qs = qbase + (hi << 2) + r;
      const int d = nt * 16 + l15;
      ctx[(size_t)qs * (NH * DH) + h * DH + d] = __float2bfloat16(o[nt][r] / lr[r]);
    }
}

}  // namespace

extern "C" void kernel_launch(void* const* d_in, const int* in_sizes, int n_in,
                              void* d_out, int out_size, void* d_ws, size_t ws_size,
                              hipStream_t stream) {
  const float* hidden = (const float*)d_in[0];
  const float* cosb = (const float*)d_in[1];
  const float* sinb = (const float*)d_in[2];
  const float* q_probs = (const float*)d_in[3];
  const float* v_norm = (const float*)d_in[4];
  const int* allowed = (const int*)d_in[5];
  const int* k_hard = (const int*)d_in[6];
  const float* Wq = (const float*)d_in[7];
  const float* Wk = (const float*)d_in[8];
  const float* Wv = (const float*)d_in[9];
  const float* Wo = (const float*)d_in[10];
  const int* sinkp = (const int*)d_in[11];
  const int* winp = (const int*)d_in[12];
  const int* Mp = (const int*)d_in[13];

  char* ws = (char*)d_ws;
  size_t off = 0;
  auto alloc = [&](size_t bytes) -> char* {
    char* p = ws + off;
    off += (bytes + 255) & ~(size_t)255;
    return p;
  };
  __hip_bfloat16* hbf = (__hip_bfloat16*)alloc((size_t)S_LEN * DM * 2);
  __hip_bfloat16* WqkvT = (__hip_bfloat16*)alloc((size_t)NQKV * DM * 2);  // packed [6144][4096]
  __hip_bfloat16* WoT = (__hip_bfloat16*)alloc((size_t)DM * DM * 2);
  __hip_bfloat16* QKV = (__hip_bfloat16*)alloc((size_t)S_LEN * NQKV * 2);
  __hip_bfloat16* Qro = (__hip_bfloat16*)alloc((size_t)S_LEN * NH * DH * 2);
  __hip_bfloat16* Kro = (__hip_bfloat16*)alloc((size_t)S_LEN * NKV * DH * 2);
  __hip_bfloat16* ctx = (__hip_bfloat16*)alloc((size_t)S_LEN * NH * DH * 2);
  int* sel_idx = (int*)alloc((size_t)NH * S_LEN * 4);
  int* sel_cnt = (int*)alloc((size_t)NH * 4);
  if (off > ws_size) return;
  // split-K partials (2 x 33.5 MB f32) overlay hbf+WqkvT, dead after QKV GEMM.
  float* Psplit = (float*)hbf;

  prep_kernel<<<12288, 256, 0, stream>>>(hidden, Wq, Wk, Wv, Wo, hbf, WqkvT, WoT);

  select_kernel<<<NH, 1024, 0, stream>>>(q_probs, v_norm, allowed, k_hard, sinkp, winp, Mp,
                                         sel_idx, sel_cnt);

  gemm_bt<false><<<dim3(NQKV / 128, S_LEN / 128), 256, 0, stream>>>(
      hbf, WqkvT, (void*)QKV, NQKV, DM);

  rope_kernel<<<S_LEN, 256, 0, stream>>>(QKV, cosb, sinb, Qro, Kro);

  attn_kernel<<<dim3(S_LEN / 64, NH), 256, 0, stream>>>(Qro, Kro, QKV + VOFF, sel_idx,
                                                        sel_cnt, ctx);

  gemm_bt_splitk<<<dim3(DM / 128, S_LEN / 128, 2), 256, 0, stream>>>(ctx, WoT, Psplit, DM,
                                                                     DM, DM / 2);
  reduce_splitk<<<(S_LEN * DM / 4 + 255) / 256, 256, 0, stream>>>((const float*)Psplit,
                                                                  (float*)d_out,
                                                                  S_LEN * DM / 4);
}

// Round 14
// 355.216 us; speedup vs baseline: 1.2258x; 1.1129x over previous
//
#include <hip/hip_runtime.h>
#include <hip/hip_bf16.h>
#include <cstdint>
#include <cstddef>

namespace {

constexpr int S_LEN = 2048;
constexpr int DM    = 4096;
constexpr int NH    = 32;
constexpr int NKV   = 8;
constexpr int DH    = 128;
constexpr int LTAB  = 20;
constexpr int RBKT  = 128;
constexpr int NQKV  = NH * DH + 2 * NKV * DH;  // 6144 packed Q|K|V cols
constexpr int KOFF  = NH * DH;                 // 4096
constexpr int VOFF  = NH * DH + NKV * DH;      // 5120

typedef short s16x8 __attribute__((ext_vector_type(8)));
typedef float f32x4 __attribute__((ext_vector_type(4)));
typedef unsigned long long u64;
struct u64x2 { u64 x, y; };

__device__ inline short bf16s(float f) {
  __hip_bfloat16 b = __float2bfloat16(f);
  return (short)*reinterpret_cast<unsigned short*>(&b);
}
__device__ inline float s2f(short s) {
  unsigned short u = (unsigned short)s;
  return __bfloat162float(*reinterpret_cast<__hip_bfloat16*>(&u));
}

// ---- merged prep+select, 1024 threads/block ----
// blocks [0,32): top-M selection (R7-proven 1024thr x 2cand geometry — do NOT
//   change to fewer threads x more candidates; R8/R10 measured 4x serial tail).
// blocks [32,544): cvt hidden f32->bf16 (4 float4/thread).
// blocks [544,3104): weight transposes, 4 x 64x64 tiles/block, 1 ld + 1 st per
//   thread per tile. LDS: keys[2048] u64 UNION 64x65 f32 tile = 16.64 KB.
__global__ __launch_bounds__(1024) void prep_select_kernel(
    const float* __restrict__ hidden, const float* __restrict__ Wq,
    const float* __restrict__ Wk, const float* __restrict__ Wv,
    const float* __restrict__ Wo, __hip_bfloat16* __restrict__ hbf,
    __hip_bfloat16* __restrict__ WqkvT, __hip_bfloat16* __restrict__ WoT,
    const float* __restrict__ q_probs, const float* __restrict__ v_norm,
    const int* __restrict__ allowed, const int* __restrict__ k_hard,
    const int* __restrict__ sinkp, const int* __restrict__ winp,
    const int* __restrict__ Mp, int* __restrict__ sel_idx, int* __restrict__ sel_cnt) {
  __shared__ __align__(16) char smem[64 * 65 * 4];  // 16640 B, unioned
  __shared__ int waveTot[16];
  const int b = blockIdx.x, tid = threadIdx.x;
  if (b < 32) {  // ---------------- selection ----------------
    u64* keys = reinterpret_cast<u64*>(smem);
    const int h = b;
    const int lane = tid & 63;
    const int wid = tid >> 6;
    const int t0 = tid * 2;
    float c0 = 0.f, c1 = 0.f;
#pragma unroll
    for (int l = 0; l < LTAB; ++l) {
      const int2 kh =
          *reinterpret_cast<const int2*>(&k_hard[(size_t)(h * LTAB + l) * S_LEN + t0]);
      c0 += q_probs[(h * LTAB + l) * RBKT + kh.x];
      c1 += q_probs[(h * LTAB + l) * RBKT + kh.y];
    }
    const int2 al = *reinterpret_cast<const int2*>(&allowed[h * S_LEN + t0]);
    const float2 vn = *reinterpret_cast<const float2*>(&v_norm[h * S_LEN + t0]);
    const float s0 = al.x ? c0 * vn.x : -INFINITY;
    const float s1 = al.y ? c1 * vn.y : -INFINITY;
    auto mkkey = [](float s, int t) -> u64 {
      unsigned m = __float_as_uint(s);
      m = (m & 0x80000000u) ? ~m : (m | 0x80000000u);
      return ((u64)m << 11) | (u64)(S_LEN - 1 - t);
    };
    const u64 k0 = mkkey(s0, t0);
    const u64 k1 = mkkey(s1, t0 + 1);
    keys[t0] = k0;
    keys[t0 + 1] = k1;
    __syncthreads();
    int r0 = 0, r1 = 0;
#pragma unroll 8
    for (int u = 0; u < S_LEN; u += 2) {
      const u64x2 kv = *reinterpret_cast<const u64x2*>(&keys[u]);
      r0 += (kv.x > k0) + (kv.y > k0);
      r1 += (kv.x > k1) + (kv.y > k1);
    }
    const int Mv = min(Mp[0], S_LEN);
    int sv = sinkp[0];
    sv = sv < 0 ? 0 : (sv > S_LEN ? S_LEN : sv);
    int wv = winp[0];
    wv = wv < 0 ? 0 : (wv > S_LEN ? S_LEN : wv);
    int wstart = S_LEN - wv;
    if (wstart < sv) wstart = sv;
    bool sel0 = r0 < Mv, sel1 = r1 < Mv;
    if (t0 < sv) sel0 = true;
    if (t0 + 1 < sv) sel1 = true;
    if (wv > 0) {
      if (t0 >= wstart) sel0 = true;
      if (t0 + 1 >= wstart) sel1 = true;
    }
    if (sv == 0 && wv == 0) {
      if (t0 == S_LEN - 1) sel0 = true;
      if (t0 + 1 == S_LEN - 1) sel1 = true;
    }
    sel0 = sel0 && (al.x != 0);
    sel1 = sel1 && (al.y != 0);
    const int cnt = (sel0 ? 1 : 0) + (sel1 ? 1 : 0);
    int inc = cnt;
#pragma unroll
    for (int off = 1; off < 64; off <<= 1) {
      int n = __shfl_up(inc, off);
      if (lane >= off) inc += n;
    }
    if (lane == 63) waveTot[wid] = inc;
    __syncthreads();
    int wbase = 0;
    for (int w = 0; w < wid; ++w) wbase += waveTot[w];
    int pos = wbase + inc - cnt;
    if (tid == 0) {
      int tot = 0;
#pragma unroll
      for (int w = 0; w < 16; ++w) tot += waveTot[w];
      sel_cnt[h] = tot;
    }
    if (sel0) sel_idx[h * S_LEN + pos++] = t0;
    if (sel1) sel_idx[h * S_LEN + pos] = t0 + 1;
    return;
  }
  if (b < 32 + 512) {  // ---------------- cvt ----------------
    const size_t base = (size_t)(b - 32) * 4096 + tid;
#pragma unroll
    for (int it = 0; it < 4; ++it) {
      const size_t i = base + it * 1024;
      float4 v = reinterpret_cast<const float4*>(hidden)[i];
      ushort4 o;
      o.x = (unsigned short)bf16s(v.x);
      o.y = (unsigned short)bf16s(v.y);
      o.z = (unsigned short)bf16s(v.z);
      o.w = (unsigned short)bf16s(v.w);
      reinterpret_cast<ushort4*>(hbf)[i] = o;
    }
    return;
  }
  // ---------------- transposes: 4 tiles per block ----------------
  float(*tile)[65] = reinterpret_cast<float(*)[65]>(smem);
  const int tbase = (b - 544) * 4;
#pragma unroll
  for (int s = 0; s < 4; ++s) {
    int t = tbase + s;
    const float* W;
    __hip_bfloat16* Wt;
    int N, bx, by;
    if (t < 4096) {
      W = Wq; Wt = WqkvT; N = DM; bx = t & 63; by = t >> 6;
    } else if (t < 5120) {
      t -= 4096; W = Wk; Wt = WqkvT + (size_t)KOFF * DM; N = NKV * DH; bx = t & 15; by = t >> 4;
    } else if (t < 6144) {
      t -= 5120; W = Wv; Wt = WqkvT + (size_t)VOFF * DM; N = NKV * DH; bx = t & 15; by = t >> 4;
    } else {
      t -= 6144; W = Wo; Wt = WoT; N = DM; bx = t & 63; by = t >> 6;
    }
    const int kb = by * 64, nb = bx * 64;
    const int r = tid >> 4, c4 = (tid & 15) * 4;
    float4 v = *reinterpret_cast<const float4*>(&W[(size_t)(kb + r) * N + nb + c4]);
    tile[r][c4] = v.x;
    tile[r][c4 + 1] = v.y;
    tile[r][c4 + 2] = v.z;
    tile[r][c4 + 3] = v.w;
    __syncthreads();
    ushort4 o;
    o.x = (unsigned short)bf16s(tile[c4][r]);
    o.y = (unsigned short)bf16s(tile[c4 + 1][r]);
    o.z = (unsigned short)bf16s(tile[c4 + 2][r]);
    o.w = (unsigned short)bf16s(tile[c4 + 3][r]);
    *reinterpret_cast<ushort4*>(&Wt[(size_t)(nb + r) * DM + kb + c4]) = o;
    __syncthreads();  // LDS reused by next tile
  }
}

// ---------------- bf16 GEMM: C[M][N] = A[M][K] * Bt[N][K]^T ----------------
// 128x128 tile, BK=64, 4 waves (2x2), mfma 16x16x32, swizzled global_load_lds staging.
// NOTE: keep LDS at exactly 32 KB and VGPR<=80 — R9/R12 measured that any epilogue
// growing either collapses occupancy (5->4 blocks/CU) and costs ~70% runtime.
template <bool OUT_F32>
__global__ __launch_bounds__(256) void gemm_bt(const __hip_bfloat16* __restrict__ A,
                                               const __hip_bfloat16* __restrict__ Bt,
                                               void* __restrict__ Cout,
                                               int N, int K) {
  __shared__ __hip_bfloat16 As[128 * 64];
  __shared__ __hip_bfloat16 Bs[128 * 64];
  const int tid = threadIdx.x;
  const int wid = tid >> 6;
  const int lane = tid & 63;
  const int bm = blockIdx.y, bn = blockIdx.x;
  const int wr = wid >> 1, wc = wid & 1;
  f32x4 acc[4][4] = {};
  const __hip_bfloat16* Abase = A + (size_t)bm * 128 * K;
  const __hip_bfloat16* Bbase = Bt + (size_t)bn * 128 * K;
  for (int kt = 0; kt < K; kt += 64) {
    __syncthreads();
#pragma unroll
    for (int j = 0; j < 4; ++j) {
      const int pb = j * 4096 + wid * 1024;
      const int p = pb + lane * 16;
      const int row = p >> 7;
      const int slot = ((p >> 4) & 7) ^ (row & 7);
      const int goff = row * K + kt + slot * 8;
      __builtin_amdgcn_global_load_lds(
          (const __attribute__((address_space(1))) void*)(Abase + goff),
          (__attribute__((address_space(3))) void*)(As + (pb >> 1)), 16, 0, 0);
      __builtin_amdgcn_global_load_lds(
          (const __attribute__((address_space(1))) void*)(Bbase + goff),
          (__attribute__((address_space(3))) void*)(Bs + (pb >> 1)), 16, 0, 0);
    }
    __syncthreads();
#pragma unroll
    for (int kk = 0; kk < 2; ++kk) {
      s16x8 af[4], bf[4];
#pragma unroll
      for (int i = 0; i < 4; ++i) {
        const int ra = wr * 64 + i * 16 + (lane & 15);
        const int sa = (kk * 4 + (lane >> 4)) ^ (ra & 7);
        af[i] = *reinterpret_cast<const s16x8*>(As + ra * 64 + sa * 8);
        const int rb = wc * 64 + i * 16 + (lane & 15);
        const int sb = (kk * 4 + (lane >> 4)) ^ (rb & 7);
        bf[i] = *reinterpret_cast<const s16x8*>(Bs + rb * 64 + sb * 8);
      }
#pragma unroll
      for (int i = 0; i < 4; ++i)
#pragma unroll
        for (int jn = 0; jn < 4; ++jn)
          acc[i][jn] = __builtin_amdgcn_mfma_f32_16x16x32_bf16(af[i], bf[jn], acc[i][jn], 0, 0, 0);
    }
  }
  const int rg = (lane >> 4) * 4;
  const int cg = lane & 15;
#pragma unroll
  for (int i = 0; i < 4; ++i)
#pragma unroll
    for (int jn = 0; jn < 4; ++jn)
#pragma unroll
      for (int r = 0; r < 4; ++r) {
        const int rr = bm * 128 + wr * 64 + i * 16 + rg + r;
        const int cc = bn * 128 + wc * 64 + jn * 16 + cg;
        if (OUT_F32)
          reinterpret_cast<float*>(Cout)[(size_t)rr * N + cc] = acc[i][jn][r];
        else
          reinterpret_cast<__hip_bfloat16*>(Cout)[(size_t)rr * N + cc] =
              __float2bfloat16(acc[i][jn][r]);
      }
}

// ---- split-K Wo GEMM: z-th K-half into P + z*M*N (f32). 1024 blocks -> 4/CU ----
__global__ __launch_bounds__(256) void gemm_bt_splitk(const __hip_bfloat16* __restrict__ A,
                                                      const __hip_bfloat16* __restrict__ Bt,
                                                      float* __restrict__ P,
                                                      int N, int Kfull, int KH) {
  __shared__ __hip_bfloat16 As[128 * 64];
  __shared__ __hip_bfloat16 Bs[128 * 64];
  const int tid = threadIdx.x;
  const int wid = tid >> 6;
  const int lane = tid & 63;
  const int bm = blockIdx.y, bn = blockIdx.x, kz = blockIdx.z;
  const int wr = wid >> 1, wc = wid & 1;
  f32x4 acc[4][4] = {};
  const __hip_bfloat16* Abase = A + (size_t)bm * 128 * Kfull + kz * KH;
  const __hip_bfloat16* Bbase = Bt + (size_t)bn * 128 * Kfull + kz * KH;
  for (int kt = 0; kt < KH; kt += 64) {
    __syncthreads();
#pragma unroll
    for (int j = 0; j < 4; ++j) {
      const int pb = j * 4096 + wid * 1024;
      const int p = pb + lane * 16;
      const int row = p >> 7;
      const int slot = ((p >> 4) & 7) ^ (row & 7);
      const int goff = row * Kfull + kt + slot * 8;
      __builtin_amdgcn_global_load_lds(
          (const __attribute__((address_space(1))) void*)(Abase + goff),
          (__attribute__((address_space(3))) void*)(As + (pb >> 1)), 16, 0, 0);
      __builtin_amdgcn_global_load_lds(
          (const __attribute__((address_space(1))) void*)(Bbase + goff),
          (__attribute__((address_space(3))) void*)(Bs + (pb >> 1)), 16, 0, 0);
    }
    __syncthreads();
#pragma unroll
    for (int kk = 0; kk < 2; ++kk) {
      s16x8 af[4], bf[4];
#pragma unroll
      for (int i = 0; i < 4; ++i) {
        const int ra = wr * 64 + i * 16 + (lane & 15);
        const int sa = (kk * 4 + (lane >> 4)) ^ (ra & 7);
        af[i] = *reinterpret_cast<const s16x8*>(As + ra * 64 + sa * 8);
        const int rb = wc * 64 + i * 16 + (lane & 15);
        const int sb = (kk * 4 + (lane >> 4)) ^ (rb & 7);
        bf[i] = *reinterpret_cast<const s16x8*>(Bs + rb * 64 + sb * 8);
      }
#pragma unroll
      for (int i = 0; i < 4; ++i)
#pragma unroll
        for (int jn = 0; jn < 4; ++jn)
          acc[i][jn] = __builtin_amdgcn_mfma_f32_16x16x32_bf16(af[i], bf[jn], acc[i][jn], 0, 0, 0);
    }
  }
  float* Pz = P + (size_t)kz * S_LEN * N;
  const int rg = (lane >> 4) * 4;
  const int cg = lane & 15;
#pragma unroll
  for (int i = 0; i < 4; ++i)
#pragma unroll
    for (int jn = 0; jn < 4; ++jn)
#pragma unroll
      for (int r = 0; r < 4; ++r) {
        const int rr = bm * 128 + wr * 64 + i * 16 + rg + r;
        const int cc = bn * 128 + wc * 64 + jn * 16 + cg;
        Pz[(size_t)rr * N + cc] = acc[i][jn][r];
      }
}

__global__ __launch_bounds__(256) void reduce_splitk(const float* __restrict__ P,
                                                     float* __restrict__ out, int n4) {
  const int i = blockIdx.x * 256 + threadIdx.x;
  if (i >= n4) return;
  const float4 a = reinterpret_cast<const float4*>(P)[i];
  const float4 b = reinterpret_cast<const float4*>(P + (size_t)S_LEN * DM)[i];
  float4 o;
  o.x = a.x + b.x;
  o.y = a.y + b.y;
  o.z = a.z + b.z;
  o.w = a.w + b.w;
  reinterpret_cast<float4*>(out)[i] = o;
}

// ---------------- RoPE on packed QKV -> Qro [S][4096], Kro [S][1024] ----------------
__global__ __launch_bounds__(256) void rope_kernel(const __hip_bfloat16* __restrict__ QKV,
                                                   const float* __restrict__ cosb,
                                                   const float* __restrict__ sinb,
                                                   __hip_bfloat16* __restrict__ Qro,
                                                   __hip_bfloat16* __restrict__ Kro) {
  const int s = blockIdx.x;
  const int tid = threadIdx.x;
  const float* cs = cosb + s * DH;
  const float* sn = sinb + s * DH;
  const __hip_bfloat16* row = QKV + (size_t)s * NQKV;
  for (int ch = tid; ch < 512 + 128; ch += 256) {
    const bool isQ = ch < 512;
    const int idx8 = (isQ ? ch : ch - 512) * 8;
    const int d8 = idx8 & (DH - 1);
    const int hb = idx8 - d8;
    const __hip_bfloat16* src = isQ ? row : row + KOFF;
    s16x8 v = *reinterpret_cast<const s16x8*>(src + idx8);
    s16x8 p = *reinterpret_cast<const s16x8*>(src + hb + (d8 ^ 64));
    const float sgn = (d8 < 64) ? -1.f : 1.f;
    s16x8 outv;
#pragma unroll
    for (int j = 0; j < 8; ++j) {
      const float r = s2f(v[j]) * cs[d8 + j] + sgn * s2f(p[j]) * sn[d8 + j];
      outv[j] = bf16s(r);
    }
    if (isQ)
      *reinterpret_cast<s16x8*>(Qro + (size_t)s * (NH * DH) + idx8) = outv;
    else
      *reinterpret_cast<s16x8*>(Kro + (size_t)s * (NKV * DH) + idx8) = outv;
  }
}

// ---------------- flash attention, BKV=64, T14 async-staged K/V ----------------
__global__ __launch_bounds__(256) void attn_kernel(const __hip_bfloat16* __restrict__ Qro,
                                                   const __hip_bfloat16* __restrict__ Kro,
                                                   const __hip_bfloat16* __restrict__ Vpk,
                                                   const int* __restrict__ sel_idx,
                                                   const int* __restrict__ sel_cnt,
                                                   __hip_bfloat16* __restrict__ ctx) {
  constexpr int BKV = 64;
  const int h = blockIdx.y;
  const int q0 = blockIdx.x * 64;
  const int tid = threadIdx.x, wid = tid >> 6, lane = tid & 63;
  const int l15 = lane & 15, hi = lane >> 4;
  const int kv = h >> 2;
  __shared__ __hip_bfloat16 Ks[BKV][DH + 8];
  __shared__ __hip_bfloat16 Vt[DH][BKV + 8];
  __shared__ __hip_bfloat16 Ps[4][16][BKV + 8];
  __shared__ int tIdx[BKV];
  const int qbase = q0 + wid * 16;
  const float scaling = 0.08838834764831845f;
  s16x8 qf[4];
  {
    const __hip_bfloat16* qp =
        Qro + (size_t)(qbase + l15) * (NH * DH) + h * DH + hi * 8;
#pragma unroll
    for (int kt = 0; kt < 4; ++kt) {
      s16x8 q = *reinterpret_cast<const s16x8*>(qp + kt * 32);
#pragma unroll
      for (int j = 0; j < 8; ++j) q[j] = bf16s(s2f(q[j]) * scaling);
      qf[kt] = q;
    }
  }
  s16x8 ones;
#pragma unroll
  for (int j = 0; j < 8; ++j) ones[j] = (short)0x3F80;
  float mr[4], lr[4];
#pragma unroll
  for (int r = 0; r < 4; ++r) {
    mr[r] = -3.0e38f;
    lr[r] = 0.f;
  }
  f32x4 o[8] = {};
  const int cnt = sel_cnt[h];
  const int qmax = q0 + 63;

  int tIdxReg = 0x7fffffff;
  s16x8 rK[4];
  s16x8 rV[4];
  const int vj = tid >> 2, vdp = (tid & 3) * 32;

  auto load_tile = [&](int j0) {
    const int nk = min(BKV, cnt - j0);
    if (tid < BKV) tIdxReg = (tid < nk) ? sel_idx[h * S_LEN + j0 + tid] : 0x7fffffff;
#pragma unroll
    for (int c = 0; c < 4; ++c) {
      const int ch = tid + c * 256;
      const int row = ch >> 4, c8 = ch & 15;
      const int t = sel_idx[h * S_LEN + j0 + min(row, nk - 1)];
      rK[c] = *reinterpret_cast<const s16x8*>(Kro + (size_t)t * (NKV * DH) + kv * DH + c8 * 8);
    }
    if (vj < nk) {
      const int t = sel_idx[h * S_LEN + j0 + vj];
      const __hip_bfloat16* vp = Vpk + (size_t)t * NQKV + kv * DH + vdp;
#pragma unroll
      for (int c = 0; c < 4; ++c) rV[c] = *reinterpret_cast<const s16x8*>(vp + c * 8);
    } else {
#pragma unroll
      for (int c = 0; c < 4; ++c) rV[c] = s16x8{};
    }
  };

  if (cnt > 0 && sel_idx[h * S_LEN] <= qmax) {
    load_tile(0);
    for (int j0 = 0; j0 < cnt; j0 += BKV) {
      const int nk = min(BKV, cnt - j0);
      __syncthreads();
      if (tid < BKV) tIdx[tid] = tIdxReg;
#pragma unroll
      for (int c = 0; c < 4; ++c) {
        const int ch = tid + c * 256;
        const int row = ch >> 4, c8 = ch & 15;
        if (row < nk) *reinterpret_cast<s16x8*>(&Ks[row][c8 * 8]) = rK[c];
      }
      {
        const int ccA = vj ^ (((vdp >> 4) & 7) << 3);
        const int ccB = vj ^ ((((vdp >> 4) + 1) & 7) << 3);
#pragma unroll
        for (int i = 0; i < 8; ++i) reinterpret_cast<short&>(Vt[vdp + i][ccA]) = rV[0][i];
#pragma unroll
        for (int i = 0; i < 8; ++i) reinterpret_cast<short&>(Vt[vdp + 8 + i][ccA]) = rV[1][i];
#pragma unroll
        for (int i = 0; i < 8; ++i) reinterpret_cast<short&>(Vt[vdp + 16 + i][ccB]) = rV[2][i];
#pragma unroll
        for (int i = 0; i < 8; ++i) reinterpret_cast<short&>(Vt[vdp + 24 + i][ccB]) = rV[3][i];
      }
      const int jn0 = j0 + BKV;
      const bool more = (jn0 < cnt) && (sel_idx[h * S_LEN + jn0] <= qmax);
      if (more) load_tile(jn0);
      __syncthreads();
      f32x4 sc[4];
#pragma unroll
      for (int kc = 0; kc < 4; ++kc) sc[kc] = f32x4{0.f, 0.f, 0.f, 0.f};
#pragma unroll
      for (int kt = 0; kt < 4; ++kt) {
#pragma unroll
        for (int kc = 0; kc < 4; ++kc) {
          const s16x8 kf =
              *reinterpret_cast<const s16x8*>(&Ks[kc * 16 + l15][kt * 32 + hi * 8]);
          sc[kc] = __builtin_amdgcn_mfma_f32_16x16x32_bf16(qf[kt], kf, sc[kc], 0, 0, 0);
        }
      }
      int tt[4];
#pragma unroll
      for (int kc = 0; kc < 4; ++kc) tt[kc] = tIdx[kc * 16 + l15];
      float vv[4][4];
      bool need = false;
#pragma unroll
      for (int r = 0; r < 4; ++r) {
        const int qs = qbase + (hi << 2) + r;
        float mx = -3.0e38f;
#pragma unroll
        for (int kc = 0; kc < 4; ++kc) {
          vv[kc][r] = (tt[kc] <= qs) ? sc[kc][r] : -1.0e9f;
          mx = fmaxf(mx, vv[kc][r]);
        }
        need = need || (mx > mr[r] + 8.f);
      }
      if (__any(need)) {
#pragma unroll
        for (int r = 0; r < 4; ++r) {
          float m = fmaxf(fmaxf(vv[0][r], vv[1][r]), fmaxf(vv[2][r], vv[3][r]));
#pragma unroll
          for (int off = 1; off < 16; off <<= 1) m = fmaxf(m, __shfl_xor(m, off));
          const float mn = fmaxf(mr[r], m);
          const float scl = __expf(mr[r] - mn);
          lr[r] *= scl;
#pragma unroll
          for (int nt = 0; nt < 8; ++nt) o[nt][r] *= scl;
          mr[r] = mn;
        }
      }
#pragma unroll
      for (int r = 0; r < 4; ++r) {
#pragma unroll
        for (int kc = 0; kc < 4; ++kc) {
          Ps[wid][(hi << 2) + r][kc * 16 + l15] = __float2bfloat16(__expf(vv[kc][r] - mr[r]));
        }
      }
      const s16x8 pf0 = *reinterpret_cast<const s16x8*>(&Ps[wid][l15][hi * 8]);
      const s16x8 pf1 = *reinterpret_cast<const s16x8*>(&Ps[wid][l15][32 + hi * 8]);
      {
        f32x4 zero = {0.f, 0.f, 0.f, 0.f};
        f32x4 ps = __builtin_amdgcn_mfma_f32_16x16x32_bf16(pf0, ones, zero, 0, 0, 0);
        ps = __builtin_amdgcn_mfma_f32_16x16x32_bf16(pf1, ones, ps, 0, 0, 0);
#pragma unroll
        for (int r = 0; r < 4; ++r) lr[r] += ps[r];
      }
#pragma unroll
      for (int nt = 0; nt < 8; ++nt) {
        const s16x8 vfa =
            *reinterpret_cast<const s16x8*>(&Vt[nt * 16 + l15][(hi * 8) ^ (nt * 8)]);
        const s16x8 vfb =
            *reinterpret_cast<const s16x8*>(&Vt[nt * 16 + l15][(32 + hi * 8) ^ (nt * 8)]);
        o[nt] = __builtin_amdgcn_mfma_f32_16x16x32_bf16(pf0, vfa, o[nt], 0, 0, 0);
        o[nt] = __builtin_amdgcn_mfma_f32_16x16x32_bf16(pf1, vfb, o[nt], 0, 0, 0);
      }
      if (!more) break;
    }
  }
#pragma unroll
  for (int nt = 0; nt < 8; ++nt)
#pragma unroll
    for (int r = 0; r < 4; ++r) {
      const int qs = qbase + (hi << 2) + r;
      const int d = nt * 16 + l15;
      ctx[(size_t)qs * (NH * DH) + h * DH + d] = __float2bfloat16(o[nt][r] / lr[r]);
    }
}

}  // namespace

extern "C" void kernel_launch(void* const* d_in, const int* in_sizes, int n_in,
                              void* d_out, int out_size, void* d_ws, size_t ws_size,
                              hipStream_t stream) {
  const float* hidden = (const float*)d_in[0];
  const float* cosb = (const float*)d_in[1];
  const float* sinb = (const float*)d_in[2];
  const float* q_probs = (const float*)d_in[3];
  const float* v_norm = (const float*)d_in[4];
  const int* allowed = (const int*)d_in[5];
  const int* k_hard = (const int*)d_in[6];
  const float* Wq = (const float*)d_in[7];
  const float* Wk = (const float*)d_in[8];
  const float* Wv = (const float*)d_in[9];
  const float* Wo = (const float*)d_in[10];
  const int* sinkp = (const int*)d_in[11];
  const int* winp = (const int*)d_in[12];
  const int* Mp = (const int*)d_in[13];

  char* ws = (char*)d_ws;
  size_t off = 0;
  auto alloc = [&](size_t bytes) -> char* {
    char* p = ws + off;
    off += (bytes + 255) & ~(size_t)255;
    return p;
  };
  __hip_bfloat16* hbf = (__hip_bfloat16*)alloc((size_t)S_LEN * DM * 2);
  __hip_bfloat16* WqkvT = (__hip_bfloat16*)alloc((size_t)NQKV * DM * 2);  // packed [6144][4096]
  __hip_bfloat16* WoT = (__hip_bfloat16*)alloc((size_t)DM * DM * 2);
  __hip_bfloat16* QKV = (__hip_bfloat16*)alloc((size_t)S_LEN * NQKV * 2);
  __hip_bfloat16* Qro = (__hip_bfloat16*)alloc((size_t)S_LEN * NH * DH * 2);
  __hip_bfloat16* Kro = (__hip_bfloat16*)alloc((size_t)S_LEN * NKV * DH * 2);
  __hip_bfloat16* ctx = (__hip_bfloat16*)alloc((size_t)S_LEN * NH * DH * 2);
  int* sel_idx = (int*)alloc((size_t)NH * S_LEN * 4);
  int* sel_cnt = (int*)alloc((size_t)NH * 4);
  if (off > ws_size) return;
  // split-K partials (2 x 33.5 MB f32) overlay hbf+WqkvT, dead after QKV GEMM.
  float* Psplit = (float*)hbf;

  prep_select_kernel<<<3104, 1024, 0, stream>>>(hidden, Wq, Wk, Wv, Wo, hbf, WqkvT, WoT,
                                                q_probs, v_norm, allowed, k_hard, sinkp,
                                                winp, Mp, sel_idx, sel_cnt);

  gemm_bt<false><<<dim3(NQKV / 128, S_LEN / 128), 256, 0, stream>>>(
      hbf, WqkvT, (void*)QKV, NQKV, DM);

  rope_kernel<<<S_LEN, 256, 0, stream>>>(QKV, cosb, sinb, Qro, Kro);

  attn_kernel<<<dim3(S_LEN / 64, NH), 256, 0, stream>>>(Qro, Kro, QKV + VOFF, sel_idx,
                                                        sel_cnt, ctx);

  gemm_bt_splitk<<<dim3(DM / 128, S_LEN / 128, 2), 256, 0, stream>>>(ctx, WoT, Psplit, DM,
                                                                     DM, DM / 2);
  reduce_splitk<<<(S_LEN * DM / 4 + 255) / 256, 256, 0, stream>>>((const float*)Psplit,
                                                                  (float*)d_out,
                                                                  S_LEN * DM / 4);
}